// Round 7
// baseline (785.158 us; speedup 1.0000x reference)
//
#include <hip/hip_runtime.h>
#include <hip/hip_bf16.h>
#include <math.h>

#define BB 16
#define TT 128
#define VV 137
#define CCH 3
#define TV (TT*VV)        // 17536 (real spatial size, for the mean divisor)
#define VP 160            // padded V
#define NP (TT*VP)        // 20480 padded spatial size
#define NCLS 226
#define APITCH 27136      // shorts per (b,t) adjacency slab (53 x 1KB DMA windows)

typedef __attribute__((ext_vector_type(8))) short bf16x8;
typedef __attribute__((ext_vector_type(4))) float f32x4;

__device__ __forceinline__ unsigned short f2bf(float x) {
  __hip_bfloat16 h = __float2bfloat16(x);
  return *reinterpret_cast<unsigned short*>(&h);
}

// swizzled LDS index (in shorts): row pitch 64 shorts, 16B-granule XOR swizzle.
__device__ __forceinline__ int swz(int row, int cg) {
  return row*64 + ((cg ^ (row & 7)) << 3);
}

// async 16B direct-to-LDS copy
__device__ __forceinline__ void gld_lds16(const unsigned short* src, unsigned short* ldst) {
  __builtin_amdgcn_global_load_lds(
      (const __attribute__((address_space(1))) void*)src,
      (__attribute__((address_space(3))) void*)ldst, 16, 0, 0);
}

// ---------------- BN stats ----------------
__global__ void bn_stats_kernel(const float* __restrict__ X,
                                const float* __restrict__ gamma,
                                const float* __restrict__ beta,
                                float* __restrict__ scale,
                                float* __restrict__ shift) {
  const int ch = blockIdx.x;           // 0..410
  const int v = ch / CCH, c = ch % CCH;
  const int tid = threadIdx.x;
  float s = 0.f, q = 0.f;
  for (int idx = tid; idx < BB*TT; idx += 256) {
    float x = X[(idx*VV + v)*CCH + c];
    s += x; q += x*x;
  }
  #pragma unroll
  for (int off = 32; off > 0; off >>= 1) {
    s += __shfl_down(s, off, 64);
    q += __shfl_down(q, off, 64);
  }
  __shared__ float ls[4], lq[4];
  const int wid = tid >> 6, lane = tid & 63;
  if (lane == 0) { ls[wid] = s; lq[wid] = q; }
  __syncthreads();
  if (tid == 0) {
    float S = ls[0]+ls[1]+ls[2]+ls[3];
    float Q = lq[0]+lq[1]+lq[2]+lq[3];
    const float inv_n = 1.f / (BB*TT);
    float mean = S * inv_n;
    float var = Q * inv_n - mean*mean;
    float sc = gamma[ch] * rsqrtf(var + 1e-5f);
    scale[ch] = sc;
    shift[ch] = beta[ch] - mean * sc;
  }
}

// ---------------- BN apply + pad to [b][n'=t*160+v][3] bf16 ----------------
__global__ void bn_apply_kernel(const float* __restrict__ X,
                                const float* __restrict__ scale,
                                const float* __restrict__ shift,
                                unsigned short* __restrict__ xn) {
  const int o = blockIdx.x*256 + threadIdx.x;
  if (o >= BB*NP*CCH) return;
  const int c = o % CCH;
  const int np = (o / CCH) % NP;
  const int b = o / (CCH*NP);
  const int t = np / VP, v = np % VP;
  float val = 0.f;
  if (v < VV) {
    const int ch = v*CCH + c;
    val = X[((b*TT + t)*VV + v)*CCH + c] * scale[ch] + shift[ch];
  }
  xn[o] = f2bf(val);
}

// ---------------- weight transpose: w[oc][ic][9] fp32 -> wT[kk][oc][ic] bf16 ----------------
__global__ void wtrans_kernel(const float* __restrict__ w, unsigned short* __restrict__ wT,
                              int OC, int IC) {
  const int o = blockIdx.x*256 + threadIdx.x;
  if (o >= OC*IC*9) return;
  const int ic = o % IC;
  const int oc = (o / IC) % OC;
  const int kk = o / (IC*OC);
  wT[o] = f2bf(w[(oc*IC + ic)*9 + kk]);
}

// ---------------- conv0 weights: w0[64][3][9] -> w0T[64][32] ----------------
__global__ void w0trans_kernel(const float* __restrict__ w0, unsigned short* __restrict__ w0T) {
  const int o = blockIdx.x*256 + threadIdx.x;
  if (o >= 64*32) return;
  const int k = o % 32, oc = o / 32;
  const int kk = k / 3, ic = k % 3;
  w0T[o] = (k < 27) ? f2bf(w0[(oc*3 + ic)*9 + kk]) : (unsigned short)0;
}

__global__ void zero_kernel(float* __restrict__ p, int n) {
  const int i = blockIdx.x*256 + threadIdx.x;
  if (i < n) p[i] = 0.f;
}

// ---------------- adjacency precompute: A[b*T+t][w*168+v] bf16 (pitch APITCH) ----------------
__global__ __launch_bounds__(256)
void adj_kernel(const float* __restrict__ X, unsigned short* __restrict__ A) {
  __shared__ float Xs[3][144];
  const int b = blockIdx.x / TT, t = blockIdx.x % TT;
  const int tid = threadIdx.x;
  for (int i = tid; i < 3*VV; i += 256) {
    const int c = i / VV, v = i % VV;
    Xs[c][v] = X[((b*TT + t)*VV + v)*CCH + c];
  }
  __syncthreads();
  unsigned short* Ab = A + (size_t)blockIdx.x * APITCH;
  for (int e = tid; e < VP*168; e += 256) {
    const int w = e / 168, v = e % 168;
    unsigned short val = 0;
    if (w < VV && v < VV) {
      const float d0 = Xs[0][v]-Xs[0][w];
      const float d1 = Xs[1][v]-Xs[1][w];
      const float d2 = Xs[2][v]-Xs[2][w];
      val = f2bf(__expf(-2.f * sqrtf(d0*d0 + d1*d1 + d2*d2)));
    }
    Ab[e] = val;
  }
}

// ---------------- conv0: K=32 im2col gather, 128n x 64oc MFMA tile ----------------
__global__ __launch_bounds__(256)
void conv0_mfma(const unsigned short* __restrict__ xn,   // [gb][NP][3] bf16
                const unsigned short* __restrict__ w0T,  // [64][32] bf16
                const float* __restrict__ bias,
                unsigned short* __restrict__ outp) {     // [gb][64][NP] bf16
  __shared__ unsigned short im_s[128*40];
  __shared__ unsigned short w_s[64*40];
  const int tid = threadIdx.x;
  const int b = blockIdx.z;
  const int n0 = blockIdx.x * 128;
  const int wave = tid >> 6, lane = tid & 63, quad = lane >> 4, l15 = lane & 15;

  {
    const int row = tid >> 2, cg = tid & 3;
    *(uint4*)&w_s[row*40 + cg*8] = *(const uint4*)(w0T + row*32 + cg*8);
  }
  for (int e = tid; e < 128*32; e += 256) {
    const int row = e >> 5, k = e & 31;
    unsigned short val = 0;
    if (k < 27) {
      const int kk = k / 3, ic = k % 3;
      const int srcn = n0 + row + (kk - 4)*VP;
      if (srcn >= 0 && srcn < NP)
        val = xn[((size_t)b*NP + srcn)*3 + ic];
    }
    im_s[row*40 + k] = val;
  }
  __syncthreads();

  f32x4 acc[2][4];
  #pragma unroll
  for (int mi = 0; mi < 2; ++mi)
    #pragma unroll
    for (int ct = 0; ct < 4; ++ct) acc[mi][ct] = (f32x4){0.f,0.f,0.f,0.f};

  bf16x8 af[2], bfr[4];
  #pragma unroll
  for (int mi = 0; mi < 2; ++mi)
    af[mi] = *(const bf16x8*)&im_s[((wave*2 + mi)*16 + l15)*40 + quad*8];
  #pragma unroll
  for (int ct = 0; ct < 4; ++ct)
    bfr[ct] = *(const bf16x8*)&w_s[(ct*16 + l15)*40 + quad*8];
  #pragma unroll
  for (int mi = 0; mi < 2; ++mi)
    #pragma unroll
    for (int ct = 0; ct < 4; ++ct)
      acc[mi][ct] = __builtin_amdgcn_mfma_f32_16x16x32_bf16(af[mi], bfr[ct], acc[mi][ct], 0, 0, 0);

  #pragma unroll
  for (int mi = 0; mi < 2; ++mi) {
    const int nbase = n0 + (wave*2 + mi)*16 + quad*4;
    #pragma unroll
    for (int ct = 0; ct < 4; ++ct) {
      const int oc = ct*16 + l15;
      const float bv = bias[oc];
      ushort4 pk;
      unsigned short* pp = (unsigned short*)&pk;
      #pragma unroll
      for (int r = 0; r < 4; ++r) {
        const int n = nbase + r;
        const int v = n - (n / VP) * VP;
        float x = acc[mi][ct][r] + bv;
        if (v >= VV) x = 0.f;
        pp[r] = f2bf(x);
      }
      *(ushort4*)(outp + ((size_t)b*64 + oc)*NP + nbase) = pk;
    }
  }
}

// ---------------- generic conv (K=9 temporal) as MFMA GEMM ----------------
// MROWS = NMT*32 output rows per block; OCB oc per block (= OCtot here, nocb=1).
// async global->LDS staging (swizzle via per-lane source perm), interior fast path,
// XCD-contiguous block swizzle.
template<int IC, int OCB, int NMT, int RELU, int FUSE>
__global__ __launch_bounds__(256)
void conv_mfma(const unsigned short* __restrict__ in,    // [gb][NP][IC] bf16
               const unsigned short* __restrict__ wT,    // [9][OCtot][IC] bf16
               const float* __restrict__ bias,
               unsigned short* __restrict__ outp,        // [gb][OCtot][NP] bf16
               float* __restrict__ mout,
               const unsigned short* __restrict__ zbuf,
               int OCtot, int ntiles) {
  constexpr int NCT = OCB / 32;            // col-tiles per wave
  constexpr int MROWS = NMT * 32;          // rows per block
  constexpr int WIN_I = MROWS / 32;        // input 1KB windows per wave
  constexpr int WIN_W = OCB / 32;          // weight 1KB windows per wave
  __shared__ unsigned short in_s[MROWS*64];
  __shared__ unsigned short w_s[OCB*64];
  const int tid = threadIdx.x;
  const int wave = tid >> 6, lane = tid & 63, quad = lane >> 4, l15 = lane & 15;

  // XCD-contiguous remap (grids divisible by 8)
  const int per = gridDim.x >> 3;
  const int lin = (blockIdx.x & 7) * per + (blockIdx.x >> 3);
  const int tile = lin % ntiles;
  const int b    = lin / ntiles;
  const int n0 = tile * MROWS;
  const int mh = (wave >> 1) * (NMT*16);    // m (n-row) half base
  const int chb = (wave & 1) * (OCB >> 1);  // col (oc) half base
  const bool interior = (n0 >= 640) && (n0 + MROWS + 640 <= NP);

  f32x4 acc[NMT][NCT];
  #pragma unroll
  for (int mt = 0; mt < NMT; ++mt)
    #pragma unroll
    for (int ct = 0; ct < NCT; ++ct) acc[mt][ct] = (f32x4){0.f,0.f,0.f,0.f};

  const int lrow = lane >> 3;               // row-in-window
  const int lcg  = lane & 7;                // granule slot in row

  for (int kk = 0; kk < 9; ++kk) {
    const int shift = (kk - 4) * VP;
    #pragma unroll
    for (int ics = 0; ics < IC; ics += 64) {
      // input staging: MROWS/8 windows of 1KB (8 rows x 64ch each)
      if (interior) {
        #pragma unroll
        for (int wi = 0; wi < WIN_I; ++wi) {
          const int W = wave + 4*wi;
          const int row = 8*W + lrow;
          const int cg = lcg ^ (row & 7);
          gld_lds16(in + ((size_t)b*NP + (n0 + shift + row))*IC + ics + cg*8,
                    in_s + W*512);
        }
      } else {
        #pragma unroll
        for (int wi = 0; wi < WIN_I; ++wi) {
          const int W = wave + 4*wi;
          const int row = 8*W + lrow;
          const int srcn = n0 + shift + row;
          const int cg = lcg ^ (row & 7);
          const unsigned short* src = (srcn >= 0 && srcn < NP)
              ? in + ((size_t)b*NP + srcn)*IC + ics + cg*8
              : zbuf + lane*8;
          gld_lds16(src, in_s + W*512);
        }
      }
      // weight staging: OCB/8 windows
      #pragma unroll
      for (int wi = 0; wi < WIN_W; ++wi) {
        const int W = wave + 4*wi;
        const int row = 8*W + lrow;
        const int cg = lcg ^ (row & 7);
        gld_lds16(wT + ((size_t)kk*OCtot + row)*IC + ics + cg*8, w_s + W*512);
      }
      __syncthreads();
      #pragma unroll
      for (int k0c = 0; k0c < 8; k0c += 4) {    // granule base: k0 in {0,32} shorts
        bf16x8 af[NMT], bfr[NCT];
        #pragma unroll
        for (int mt = 0; mt < NMT; ++mt)
          af[mt] = *(const bf16x8*)&in_s[swz(mh + mt*16 + l15, k0c + quad)];
        #pragma unroll
        for (int ct = 0; ct < NCT; ++ct)
          bfr[ct] = *(const bf16x8*)&w_s[swz(chb + ct*16 + l15, k0c + quad)];
        #pragma unroll
        for (int mt = 0; mt < NMT; ++mt)
          #pragma unroll
          for (int ct = 0; ct < NCT; ++ct)
            acc[mt][ct] = __builtin_amdgcn_mfma_f32_16x16x32_bf16(af[mt], bfr[ct], acc[mt][ct], 0, 0, 0);
      }
      __syncthreads();
    }
  }

  if (!FUSE) {
    #pragma unroll
    for (int mt = 0; mt < NMT; ++mt) {
      const int nbase = n0 + mh + mt*16 + quad*4;
      #pragma unroll
      for (int ct = 0; ct < NCT; ++ct) {
        const int oc = chb + ct*16 + l15;
        const float bv = bias[oc];
        ushort4 pk;
        unsigned short* pp = (unsigned short*)&pk;
        #pragma unroll
        for (int r = 0; r < 4; ++r) {
          const int n = nbase + r;
          const int v = n - (n / VP) * VP;
          float x = acc[mt][ct][r] + bv;
          if (RELU) x = fmaxf(x, 0.f);
          if (v >= VV) x = 0.f;
          pp[r] = f2bf(x);
        }
        *(ushort4*)(outp + ((size_t)b*OCtot + oc)*NP + nbase) = pk;
      }
    }
  } else {
    #pragma unroll
    for (int ct = 0; ct < NCT; ++ct) {
      const int oc = chb + ct*16 + l15;
      const float bv = bias[oc];
      float s = 0.f;
      #pragma unroll
      for (int mt = 0; mt < NMT; ++mt) {
        const int nbase = n0 + mh + mt*16 + quad*4;
        #pragma unroll
        for (int r = 0; r < 4; ++r) {
          const int n = nbase + r;
          const int v = n - (n / VP) * VP;
          float x = acc[mt][ct][r] + bv;
          if (RELU) x = fmaxf(x, 0.f);
          if (v < VV) s += x;
        }
      }
      s += __shfl_down(s, 32, 64);
      s += __shfl_down(s, 16, 64);
      if (lane < 16) atomicAdd(&mout[(size_t)b*OCtot + oc], s * (1.f / TV));
    }
  }
}

// ---------------- graph matmul (MFMA), adjacency DMA'd from precomputed buffer ----------------
// act: [gb][Cin][NP] bf16 -> out: [gb][NP][Cin] bf16;  Cin = 64*MPW
template<int MPW>
__global__ __launch_bounds__(256)
void gmm_mfma(const unsigned short* __restrict__ A,   // [gb*T][APITCH] bf16
              const unsigned short* __restrict__ act,
              unsigned short* __restrict__ outp) {
  constexpr int Cin = 64 * MPW;
  __shared__ unsigned short As[APITCH];   // 54,272 B (valid region: 160x168)
  const int b = blockIdx.x / TT, t = blockIdx.x % TT;
  const int tid = threadIdx.x;
  const int wave = tid >> 6, lane = tid & 63, quad = lane >> 4, l15 = lane & 15;

  // DMA the adjacency slab: 53 x 1KB windows (last window over-reads into slab pad)
  const unsigned short* Abt = A + (size_t)blockIdx.x * APITCH;
  for (int W = wave; W < 53; W += 4)
    gld_lds16(Abt + W*512 + lane*8, As + W*512);
  __syncthreads();

  f32x4 acc[MPW][10];
  #pragma unroll
  for (int mi = 0; mi < MPW; ++mi)
    #pragma unroll
    for (int ct = 0; ct < 10; ++ct) acc[mi][ct] = (f32x4){0.f,0.f,0.f,0.f};

  #pragma unroll
  for (int k0 = 0; k0 < VP; k0 += 32) {
    bf16x8 af[MPW];
    #pragma unroll
    for (int mi = 0; mi < MPW; ++mi) {
      const int c = (wave*MPW + mi)*16 + l15;
      af[mi] = *(const bf16x8*)(act + ((size_t)b*Cin + c)*NP + t*VP + k0 + quad*8);
    }
    #pragma unroll
    for (int ct = 0; ct < 10; ++ct) {
      const bf16x8 bfv = *(const bf16x8*)&As[(ct*16 + l15)*168 + k0 + quad*8];
      #pragma unroll
      for (int mi = 0; mi < MPW; ++mi)
        acc[mi][ct] = __builtin_amdgcn_mfma_f32_16x16x32_bf16(af[mi], bfv, acc[mi][ct], 0, 0, 0);
    }
  }

  #pragma unroll
  for (int mi = 0; mi < MPW; ++mi) {
    const int m0 = (wave*MPW + mi)*16;
    #pragma unroll
    for (int ct = 0; ct < 10; ++ct) {
      const int w = ct*16 + l15;
      const bool wok = (w < VV);
      ushort4 pk;
      unsigned short* pp = (unsigned short*)&pk;
      #pragma unroll
      for (int r = 0; r < 4; ++r)
        pp[r] = f2bf(wok ? acc[mi][ct][r] : 0.f);
      *(ushort4*)(outp + ((size_t)b*NP + t*VP + w)*Cin + m0 + quad*4) = pk;
    }
  }
}

// ---------------- FC ----------------
__global__ void fc_kernel(const float* __restrict__ mean,
                          const float* __restrict__ fcw,
                          const float* __restrict__ fcb,
                          float* __restrict__ out) {
  const int b = blockIdx.x;
  __shared__ float ms[256];
  const int tid = threadIdx.x;
  ms[tid] = mean[b*256 + tid];
  __syncthreads();
  if (tid < NCLS) {
    float acc = fcb[tid];
    for (int c = 0; c < 256; ++c) acc = fmaf(ms[c], fcw[tid*256 + c], acc);
    out[b*NCLS + tid] = acc;
  }
}

extern "C" void kernel_launch(void* const* d_in, const int* in_sizes, int n_in,
                              void* d_out, int out_size, void* d_ws, size_t ws_size,
                              hipStream_t stream) {
  const float* X    = (const float*)d_in[0];
  const float* bn_g = (const float*)d_in[1];
  const float* bn_b = (const float*)d_in[2];
  const float* w0   = (const float*)d_in[3];
  const float* cb0  = (const float*)d_in[4];
  const float* w1   = (const float*)d_in[5];
  const float* cb1  = (const float*)d_in[6];
  const float* w2   = (const float*)d_in[7];
  const float* cb2  = (const float*)d_in[8];
  const float* w3   = (const float*)d_in[9];
  const float* cb3  = (const float*)d_in[10];
  const float* fcw  = (const float*)d_in[11];
  const float* fcb  = (const float*)d_in[12];
  float* out = (float*)d_out;

  unsigned char* W = (unsigned char*)d_ws;
  size_t off = 0;
  auto alloc = [&](size_t bytes) -> void* {
    void* p = W + off;
    off += (bytes + 255) & ~(size_t)255;
    return p;
  };
  float* meanb  = (float*)alloc(BB*256*4);        // 16 KB
  float* zbuf_f = (float*)alloc(2048);            // 2 KB zero page
  float* scale  = (float*)alloc(512*4);
  float* shiftb = (float*)alloc(512*4);
  unsigned short* w0T = (unsigned short*)alloc(64*32*2);
  unsigned short* wT1 = (unsigned short*)alloc((size_t)9*64*64*2);
  unsigned short* wT2 = (unsigned short*)alloc((size_t)9*128*64*2);
  unsigned short* wT3 = (unsigned short*)alloc((size_t)9*256*128*2);
  unsigned short* xn  = (unsigned short*)alloc((size_t)BB*NP*3*2);
  const size_t fixedB = off;
  // per-batch: P + Q (bf16 128ch x NP) + adjacency slab (T x APITCH)
  const size_t perB = 2*((size_t)128*NP*2 + 256) + ((size_t)TT*APITCH*2 + 256);

  int g = 1;
  if (ws_size > fixedB + perB) {
    size_t gg = (ws_size - fixedB) / perB;
    g = (gg >= BB) ? BB : (int)gg;
  }
  unsigned short* P  = (unsigned short*)alloc((size_t)g*128*NP*2);
  unsigned short* Q  = (unsigned short*)alloc((size_t)g*128*NP*2);
  unsigned short* Ab = (unsigned short*)alloc((size_t)g*TT*APITCH*2);
  const unsigned short* zbuf = (const unsigned short*)zbuf_f;

  bn_stats_kernel<<<411, 256, 0, stream>>>(X, bn_g, bn_b, scale, shiftb);
  bn_apply_kernel<<<(BB*NP*3 + 255)/256, 256, 0, stream>>>(X, scale, shiftb, xn);
  w0trans_kernel<<<(64*32 + 255)/256, 256, 0, stream>>>(w0, w0T);
  wtrans_kernel<<<(9*64*64   + 255)/256, 256, 0, stream>>>(w1, wT1, 64, 64);
  wtrans_kernel<<<(9*128*64  + 255)/256, 256, 0, stream>>>(w2, wT2, 128, 64);
  wtrans_kernel<<<(9*256*128 + 255)/256, 256, 0, stream>>>(w3, wT3, 256, 128);
  zero_kernel<<<((BB*256 + 512) + 255)/256, 256, 0, stream>>>(meanb, BB*256 + 512);

  const int nt128 = NP / 128;  // 160 (conv0, conv2, conv3)
  const int nt256 = NP / 256;  // 80  (conv1)

  for (int b0 = 0; b0 < BB; b0 += g) {
    const int gb = (BB - b0 < g) ? (BB - b0) : g;
    const float* Xg = X + (size_t)b0 * TT * VV * CCH;
    const unsigned short* xng = xn + (size_t)b0 * NP * 3;
    float* mg = meanb + (size_t)b0 * 256;

    // adjacency once per group
    adj_kernel<<<gb*TT, 256, 0, stream>>>(Xg, Ab);
    // conv0: xn(3ch) -> P[64][NP]
    conv0_mfma<<<dim3(nt128,1,gb), 256, 0, stream>>>(xng, w0T, cb0, P);
    // layer 1
    gmm_mfma<1><<<gb*TT, 256, 0, stream>>>(Ab, P, Q);
    conv_mfma<64,64,8,1,0><<<nt256*gb, 256, 0, stream>>>(Q, wT1, cb1, P, nullptr, zbuf, 64, nt256);
    // layer 2
    gmm_mfma<1><<<gb*TT, 256, 0, stream>>>(Ab, P, Q);
    conv_mfma<64,128,4,1,0><<<nt128*gb, 256, 0, stream>>>(Q, wT2, cb2, P, nullptr, zbuf, 128, nt128);
    // layer 3 (conv3: all 256 oc in one block, fused relu+mean)
    gmm_mfma<2><<<gb*TT, 256, 0, stream>>>(Ab, P, Q);
    conv_mfma<128,256,4,1,1><<<nt128*gb, 256, 0, stream>>>(Q, wT3, cb3, nullptr, mg, zbuf, 256, nt128);
  }

  fc_kernel<<<BB, 256, 0, stream>>>(meanb, fcw, fcb, out);
}

// Round 8
// 748.380 us; speedup vs baseline: 1.0491x; 1.0491x over previous
//
#include <hip/hip_runtime.h>
#include <hip/hip_bf16.h>
#include <math.h>

#define BB 16
#define TT 128
#define VV 137
#define CCH 3
#define TV (TT*VV)        // 17536 (real spatial size, for the mean divisor)
#define VP 160            // padded V
#define NP (TT*VP)        // 20480 padded spatial size
#define NCLS 226
#define APITCH 27136      // shorts per (b,t) adjacency slab (53 x 1KB DMA windows)

typedef __attribute__((ext_vector_type(8))) short bf16x8;
typedef __attribute__((ext_vector_type(4))) float f32x4;

__device__ __forceinline__ unsigned short f2bf(float x) {
  __hip_bfloat16 h = __float2bfloat16(x);
  return *reinterpret_cast<unsigned short*>(&h);
}

// swizzled LDS index (in shorts): row pitch 64 shorts, 16B-granule XOR swizzle.
__device__ __forceinline__ int swz(int row, int cg) {
  return row*64 + ((cg ^ (row & 7)) << 3);
}

// async 16B direct-to-LDS copy
__device__ __forceinline__ void gld_lds16(const unsigned short* src, unsigned short* ldst) {
  __builtin_amdgcn_global_load_lds(
      (const __attribute__((address_space(1))) void*)src,
      (__attribute__((address_space(3))) void*)ldst, 16, 0, 0);
}

// ---------------- BN stats ----------------
__global__ void bn_stats_kernel(const float* __restrict__ X,
                                const float* __restrict__ gamma,
                                const float* __restrict__ beta,
                                float* __restrict__ scale,
                                float* __restrict__ shift) {
  const int ch = blockIdx.x;           // 0..410
  const int v = ch / CCH, c = ch % CCH;
  const int tid = threadIdx.x;
  float s = 0.f, q = 0.f;
  for (int idx = tid; idx < BB*TT; idx += 256) {
    float x = X[(idx*VV + v)*CCH + c];
    s += x; q += x*x;
  }
  #pragma unroll
  for (int off = 32; off > 0; off >>= 1) {
    s += __shfl_down(s, off, 64);
    q += __shfl_down(q, off, 64);
  }
  __shared__ float ls[4], lq[4];
  const int wid = tid >> 6, lane = tid & 63;
  if (lane == 0) { ls[wid] = s; lq[wid] = q; }
  __syncthreads();
  if (tid == 0) {
    float S = ls[0]+ls[1]+ls[2]+ls[3];
    float Q = lq[0]+lq[1]+lq[2]+lq[3];
    const float inv_n = 1.f / (BB*TT);
    float mean = S * inv_n;
    float var = Q * inv_n - mean*mean;
    float sc = gamma[ch] * rsqrtf(var + 1e-5f);
    scale[ch] = sc;
    shift[ch] = beta[ch] - mean * sc;
  }
}

// ---------------- BN apply + pad to [b][n'=t*160+v][3] bf16 ----------------
__global__ void bn_apply_kernel(const float* __restrict__ X,
                                const float* __restrict__ scale,
                                const float* __restrict__ shift,
                                unsigned short* __restrict__ xn) {
  const int o = blockIdx.x*256 + threadIdx.x;
  if (o >= BB*NP*CCH) return;
  const int c = o % CCH;
  const int np = (o / CCH) % NP;
  const int b = o / (CCH*NP);
  const int t = np / VP, v = np % VP;
  float val = 0.f;
  if (v < VV) {
    const int ch = v*CCH + c;
    val = X[((b*TT + t)*VV + v)*CCH + c] * scale[ch] + shift[ch];
  }
  xn[o] = f2bf(val);
}

// ---------------- weight transpose: w[oc][ic][9] fp32 -> wT[kk][oc][ic] bf16 ----------------
__global__ void wtrans_kernel(const float* __restrict__ w, unsigned short* __restrict__ wT,
                              int OC, int IC) {
  const int o = blockIdx.x*256 + threadIdx.x;
  if (o >= OC*IC*9) return;
  const int ic = o % IC;
  const int oc = (o / IC) % OC;
  const int kk = o / (IC*OC);
  wT[o] = f2bf(w[(oc*IC + ic)*9 + kk]);
}

// ---------------- conv0 weights: w0[64][3][9] -> w0T[64][32] ----------------
__global__ void w0trans_kernel(const float* __restrict__ w0, unsigned short* __restrict__ w0T) {
  const int o = blockIdx.x*256 + threadIdx.x;
  if (o >= 64*32) return;
  const int k = o % 32, oc = o / 32;
  const int kk = k / 3, ic = k % 3;
  w0T[o] = (k < 27) ? f2bf(w0[(oc*3 + ic)*9 + kk]) : (unsigned short)0;
}

__global__ void zero_kernel(float* __restrict__ p, int n) {
  const int i = blockIdx.x*256 + threadIdx.x;
  if (i < n) p[i] = 0.f;
}

// ---------------- adjacency precompute: A[b*T+t][w*168+v] bf16 (pitch APITCH) ----------------
__global__ __launch_bounds__(256)
void adj_kernel(const float* __restrict__ X, unsigned short* __restrict__ A) {
  __shared__ float Xs[3][144];
  const int b = blockIdx.x / TT, t = blockIdx.x % TT;
  const int tid = threadIdx.x;
  for (int i = tid; i < 3*VV; i += 256) {
    const int c = i / VV, v = i % VV;
    Xs[c][v] = X[((b*TT + t)*VV + v)*CCH + c];
  }
  __syncthreads();
  unsigned short* Ab = A + (size_t)blockIdx.x * APITCH;
  for (int e = tid; e < VP*168; e += 256) {
    const int w = e / 168, v = e % 168;
    unsigned short val = 0;
    if (w < VV && v < VV) {
      const float d0 = Xs[0][v]-Xs[0][w];
      const float d1 = Xs[1][v]-Xs[1][w];
      const float d2 = Xs[2][v]-Xs[2][w];
      val = f2bf(__expf(-2.f * sqrtf(d0*d0 + d1*d1 + d2*d2)));
    }
    Ab[e] = val;
  }
}

// ---------------- conv0: K=32 im2col gather, 128n x 64oc MFMA tile ----------------
__global__ __launch_bounds__(256)
void conv0_mfma(const unsigned short* __restrict__ xn,   // [gb][NP][3] bf16
                const unsigned short* __restrict__ w0T,  // [64][32] bf16
                const float* __restrict__ bias,
                unsigned short* __restrict__ outp) {     // [gb][64][NP] bf16
  __shared__ unsigned short im_s[128*40];
  __shared__ unsigned short w_s[64*40];
  const int tid = threadIdx.x;
  const int b = blockIdx.z;
  const int n0 = blockIdx.x * 128;
  const int wave = tid >> 6, lane = tid & 63, quad = lane >> 4, l15 = lane & 15;

  {
    const int row = tid >> 2, cg = tid & 3;
    *(uint4*)&w_s[row*40 + cg*8] = *(const uint4*)(w0T + row*32 + cg*8);
  }
  for (int e = tid; e < 128*32; e += 256) {
    const int row = e >> 5, k = e & 31;
    unsigned short val = 0;
    if (k < 27) {
      const int kk = k / 3, ic = k % 3;
      const int srcn = n0 + row + (kk - 4)*VP;
      if (srcn >= 0 && srcn < NP)
        val = xn[((size_t)b*NP + srcn)*3 + ic];
    }
    im_s[row*40 + k] = val;
  }
  __syncthreads();

  f32x4 acc[2][4];
  #pragma unroll
  for (int mi = 0; mi < 2; ++mi)
    #pragma unroll
    for (int ct = 0; ct < 4; ++ct) acc[mi][ct] = (f32x4){0.f,0.f,0.f,0.f};

  bf16x8 af[2], bfr[4];
  #pragma unroll
  for (int mi = 0; mi < 2; ++mi)
    af[mi] = *(const bf16x8*)&im_s[((wave*2 + mi)*16 + l15)*40 + quad*8];
  #pragma unroll
  for (int ct = 0; ct < 4; ++ct)
    bfr[ct] = *(const bf16x8*)&w_s[(ct*16 + l15)*40 + quad*8];
  #pragma unroll
  for (int mi = 0; mi < 2; ++mi)
    #pragma unroll
    for (int ct = 0; ct < 4; ++ct)
      acc[mi][ct] = __builtin_amdgcn_mfma_f32_16x16x32_bf16(af[mi], bfr[ct], acc[mi][ct], 0, 0, 0);

  #pragma unroll
  for (int mi = 0; mi < 2; ++mi) {
    const int nbase = n0 + (wave*2 + mi)*16 + quad*4;
    #pragma unroll
    for (int ct = 0; ct < 4; ++ct) {
      const int oc = ct*16 + l15;
      const float bv = bias[oc];
      ushort4 pk;
      unsigned short* pp = (unsigned short*)&pk;
      #pragma unroll
      for (int r = 0; r < 4; ++r) {
        const int n = nbase + r;
        const int v = n - (n / VP) * VP;
        float x = acc[mi][ct][r] + bv;
        if (v >= VV) x = 0.f;
        pp[r] = f2bf(x);
      }
      *(ushort4*)(outp + ((size_t)b*64 + oc)*NP + nbase) = pk;
    }
  }
}

// ---------------- generic conv (K=9 temporal) as MFMA GEMM ----------------
// Single-barrier double-buffered staging: DMA for phase p+1 is issued before
// compute of phase p; the one __syncthreads per phase drains it after compute.
template<int IC, int OCB, int NMT, int RELU, int FUSE>
__global__ __launch_bounds__(256)
void conv_mfma(const unsigned short* __restrict__ in,    // [gb][NP][IC] bf16
               const unsigned short* __restrict__ wT,    // [9][OCtot][IC] bf16
               const float* __restrict__ bias,
               unsigned short* __restrict__ outp,        // [gb][OCtot][NP] bf16
               float* __restrict__ mout,
               const unsigned short* __restrict__ zbuf,
               int OCtot, int ntiles, int nocb) {
  constexpr int NCT = OCB / 32;            // col-tiles per wave
  constexpr int MROWS = NMT * 32;          // rows per block
  constexpr int WIN_I = MROWS / 32;        // input 1KB windows per wave per phase
  constexpr int WIN_W = OCB / 32;          // weight 1KB windows per wave per phase
  constexpr int NICS = IC / 64;            // ics chunks (1 or 2)
  constexpr int NPH = 9 * NICS;            // total phases
  __shared__ unsigned short in_s[2][MROWS*64];
  __shared__ unsigned short w_s[2][OCB*64];
  const int tid = threadIdx.x;
  const int wave = tid >> 6, lane = tid & 63, quad = lane >> 4, l15 = lane & 15;

  // XCD-contiguous remap (grids divisible by 8)
  const int per = gridDim.x >> 3;
  const int lin = (blockIdx.x & 7) * per + (blockIdx.x >> 3);
  const int tile = lin % ntiles;
  const int ocby = (lin / ntiles) % nocb;
  const int b    = lin / (ntiles * nocb);
  const int ocb0 = ocby * OCB;
  const int n0 = tile * MROWS;
  const int mh = (wave >> 1) * (NMT*16);    // m (n-row) half base
  const int chb = (wave & 1) * (OCB >> 1);  // col (oc) half base
  const bool interior = (n0 >= 640) && (n0 + MROWS + 640 <= NP);

  const int lrow = lane >> 3;               // row-in-window
  const int lcg  = lane & 7;                // granule slot in row

  // stage phase p into buffer bi
  auto stage = [&](int p, int bi) {
    const int kk = (NICS == 2) ? (p >> 1) : p;
    const int ics = (NICS == 2) ? ((p & 1) * 64) : 0;
    const int shift = (kk - 4) * VP;
    if (interior) {
      #pragma unroll
      for (int wi = 0; wi < WIN_I; ++wi) {
        const int W = wave + 4*wi;
        const int row = 8*W + lrow;
        const int cg = lcg ^ (row & 7);
        gld_lds16(in + ((size_t)b*NP + (n0 + shift + row))*IC + ics + cg*8,
                  &in_s[bi][W*512]);
      }
    } else {
      #pragma unroll
      for (int wi = 0; wi < WIN_I; ++wi) {
        const int W = wave + 4*wi;
        const int row = 8*W + lrow;
        const int srcn = n0 + shift + row;
        const int cg = lcg ^ (row & 7);
        const unsigned short* src = (srcn >= 0 && srcn < NP)
            ? in + ((size_t)b*NP + srcn)*IC + ics + cg*8
            : zbuf + lane*8;
        gld_lds16(src, &in_s[bi][W*512]);
      }
    }
    #pragma unroll
    for (int wi = 0; wi < WIN_W; ++wi) {
      const int W = wave + 4*wi;
      const int row = 8*W + lrow;
      const int cg = lcg ^ (row & 7);
      gld_lds16(wT + ((size_t)kk*OCtot + ocb0 + row)*IC + ics + cg*8,
                &w_s[bi][W*512]);
    }
  };

  f32x4 acc[NMT][NCT];
  #pragma unroll
  for (int mt = 0; mt < NMT; ++mt)
    #pragma unroll
    for (int ct = 0; ct < NCT; ++ct) acc[mt][ct] = (f32x4){0.f,0.f,0.f,0.f};

  stage(0, 0);
  __syncthreads();

  for (int p = 0; p < NPH; ++p) {
    const int pn = (p + 1 < NPH) ? (p + 1) : p;   // final phase re-stages (unused)
    stage(pn, (p + 1) & 1);
    const int cb = p & 1;
    #pragma unroll
    for (int k0c = 0; k0c < 8; k0c += 4) {    // granule base: k0 in {0,32} shorts
      bf16x8 af[NMT], bfr[NCT];
      #pragma unroll
      for (int mt = 0; mt < NMT; ++mt)
        af[mt] = *(const bf16x8*)&in_s[cb][swz(mh + mt*16 + l15, k0c + quad)];
      #pragma unroll
      for (int ct = 0; ct < NCT; ++ct)
        bfr[ct] = *(const bf16x8*)&w_s[cb][swz(chb + ct*16 + l15, k0c + quad)];
      #pragma unroll
      for (int mt = 0; mt < NMT; ++mt)
        #pragma unroll
        for (int ct = 0; ct < NCT; ++ct)
          acc[mt][ct] = __builtin_amdgcn_mfma_f32_16x16x32_bf16(af[mt], bfr[ct], acc[mt][ct], 0, 0, 0);
    }
    __syncthreads();   // drains vmcnt(0): pn staging complete; buffers safe to swap
  }

  if (!FUSE) {
    #pragma unroll
    for (int mt = 0; mt < NMT; ++mt) {
      const int nbase = n0 + mh + mt*16 + quad*4;
      #pragma unroll
      for (int ct = 0; ct < NCT; ++ct) {
        const int oc = ocb0 + chb + ct*16 + l15;
        const float bv = bias[oc];
        ushort4 pk;
        unsigned short* pp = (unsigned short*)&pk;
        #pragma unroll
        for (int r = 0; r < 4; ++r) {
          const int n = nbase + r;
          const int v = n - (n / VP) * VP;
          float x = acc[mt][ct][r] + bv;
          if (RELU) x = fmaxf(x, 0.f);
          if (v >= VV) x = 0.f;
          pp[r] = f2bf(x);
        }
        *(ushort4*)(outp + ((size_t)b*OCtot + oc)*NP + nbase) = pk;
      }
    }
  } else {
    #pragma unroll
    for (int ct = 0; ct < NCT; ++ct) {
      const int oc = ocb0 + chb + ct*16 + l15;
      const float bv = bias[oc];
      float s = 0.f;
      #pragma unroll
      for (int mt = 0; mt < NMT; ++mt) {
        const int nbase = n0 + mh + mt*16 + quad*4;
        #pragma unroll
        for (int r = 0; r < 4; ++r) {
          const int n = nbase + r;
          const int v = n - (n / VP) * VP;
          float x = acc[mt][ct][r] + bv;
          if (RELU) x = fmaxf(x, 0.f);
          if (v < VV) s += x;
        }
      }
      s += __shfl_down(s, 32, 64);
      s += __shfl_down(s, 16, 64);
      if (lane < 16) atomicAdd(&mout[(size_t)b*OCtot + oc], s * (1.f / TV));
    }
  }
}

// ---------------- graph matmul (MFMA), adjacency DMA'd from precomputed buffer ----------------
// act: [gb][Cin][NP] bf16 -> out: [gb][NP][Cin] bf16;  Cin = 64*MPW
template<int MPW>
__global__ __launch_bounds__(256)
void gmm_mfma(const unsigned short* __restrict__ A,   // [gb*T][APITCH] bf16
              const unsigned short* __restrict__ act,
              unsigned short* __restrict__ outp) {
  constexpr int Cin = 64 * MPW;
  __shared__ unsigned short As[APITCH];   // 54,272 B (valid region: 160x168)
  const int b = blockIdx.x / TT, t = blockIdx.x % TT;
  const int tid = threadIdx.x;
  const int wave = tid >> 6, lane = tid & 63, quad = lane >> 4, l15 = lane & 15;

  // DMA the adjacency slab: 53 x 1KB windows
  const unsigned short* Abt = A + (size_t)blockIdx.x * APITCH;
  for (int W = wave; W < 53; W += 4)
    gld_lds16(Abt + W*512 + lane*8, As + W*512);
  __syncthreads();

  f32x4 acc[MPW][10];
  #pragma unroll
  for (int mi = 0; mi < MPW; ++mi)
    #pragma unroll
    for (int ct = 0; ct < 10; ++ct) acc[mi][ct] = (f32x4){0.f,0.f,0.f,0.f};

  #pragma unroll
  for (int k0 = 0; k0 < VP; k0 += 32) {
    bf16x8 af[MPW];
    #pragma unroll
    for (int mi = 0; mi < MPW; ++mi) {
      const int c = (wave*MPW + mi)*16 + l15;
      af[mi] = *(const bf16x8*)(act + ((size_t)b*Cin + c)*NP + t*VP + k0 + quad*8);
    }
    #pragma unroll
    for (int ct = 0; ct < 10; ++ct) {
      const bf16x8 bfv = *(const bf16x8*)&As[(ct*16 + l15)*168 + k0 + quad*8];
      #pragma unroll
      for (int mi = 0; mi < MPW; ++mi)
        acc[mi][ct] = __builtin_amdgcn_mfma_f32_16x16x32_bf16(af[mi], bfv, acc[mi][ct], 0, 0, 0);
    }
  }

  #pragma unroll
  for (int mi = 0; mi < MPW; ++mi) {
    const int m0 = (wave*MPW + mi)*16;
    #pragma unroll
    for (int ct = 0; ct < 10; ++ct) {
      const int w = ct*16 + l15;
      const bool wok = (w < VV);
      ushort4 pk;
      unsigned short* pp = (unsigned short*)&pk;
      #pragma unroll
      for (int r = 0; r < 4; ++r)
        pp[r] = f2bf(wok ? acc[mi][ct][r] : 0.f);
      *(ushort4*)(outp + ((size_t)b*NP + t*VP + w)*Cin + m0 + quad*4) = pk;
    }
  }
}

// ---------------- FC ----------------
__global__ void fc_kernel(const float* __restrict__ mean,
                          const float* __restrict__ fcw,
                          const float* __restrict__ fcb,
                          float* __restrict__ out) {
  const int b = blockIdx.x;
  __shared__ float ms[256];
  const int tid = threadIdx.x;
  ms[tid] = mean[b*256 + tid];
  __syncthreads();
  if (tid < NCLS) {
    float acc = fcb[tid];
    for (int c = 0; c < 256; ++c) acc = fmaf(ms[c], fcw[tid*256 + c], acc);
    out[b*NCLS + tid] = acc;
  }
}

extern "C" void kernel_launch(void* const* d_in, const int* in_sizes, int n_in,
                              void* d_out, int out_size, void* d_ws, size_t ws_size,
                              hipStream_t stream) {
  const float* X    = (const float*)d_in[0];
  const float* bn_g = (const float*)d_in[1];
  const float* bn_b = (const float*)d_in[2];
  const float* w0   = (const float*)d_in[3];
  const float* cb0  = (const float*)d_in[4];
  const float* w1   = (const float*)d_in[5];
  const float* cb1  = (const float*)d_in[6];
  const float* w2   = (const float*)d_in[7];
  const float* cb2  = (const float*)d_in[8];
  const float* w3   = (const float*)d_in[9];
  const float* cb3  = (const float*)d_in[10];
  const float* fcw  = (const float*)d_in[11];
  const float* fcb  = (const float*)d_in[12];
  float* out = (float*)d_out;

  unsigned char* W = (unsigned char*)d_ws;
  size_t off = 0;
  auto alloc = [&](size_t bytes) -> void* {
    void* p = W + off;
    off += (bytes + 255) & ~(size_t)255;
    return p;
  };
  float* meanb  = (float*)alloc(BB*256*4);        // 16 KB
  float* zbuf_f = (float*)alloc(2048);            // 2 KB zero page
  float* scale  = (float*)alloc(512*4);
  float* shiftb = (float*)alloc(512*4);
  unsigned short* w0T = (unsigned short*)alloc(64*32*2);
  unsigned short* wT1 = (unsigned short*)alloc((size_t)9*64*64*2);
  unsigned short* wT2 = (unsigned short*)alloc((size_t)9*128*64*2);
  unsigned short* wT3 = (unsigned short*)alloc((size_t)9*256*128*2);
  unsigned short* xn  = (unsigned short*)alloc((size_t)BB*NP*3*2);
  const size_t fixedB = off;
  // per-batch: P + Q (bf16 128ch x NP) + adjacency slab (T x APITCH)
  const size_t perB = 2*((size_t)128*NP*2 + 256) + ((size_t)TT*APITCH*2 + 256);

  int g = 1;
  if (ws_size > fixedB + perB) {
    size_t gg = (ws_size - fixedB) / perB;
    g = (gg >= BB) ? BB : (int)gg;
  }
  unsigned short* P  = (unsigned short*)alloc((size_t)g*128*NP*2);
  unsigned short* Q  = (unsigned short*)alloc((size_t)g*128*NP*2);
  unsigned short* Ab = (unsigned short*)alloc((size_t)g*TT*APITCH*2);
  const unsigned short* zbuf = (const unsigned short*)zbuf_f;

  bn_stats_kernel<<<411, 256, 0, stream>>>(X, bn_g, bn_b, scale, shiftb);
  bn_apply_kernel<<<(BB*NP*3 + 255)/256, 256, 0, stream>>>(X, scale, shiftb, xn);
  w0trans_kernel<<<(64*32 + 255)/256, 256, 0, stream>>>(w0, w0T);
  wtrans_kernel<<<(9*64*64   + 255)/256, 256, 0, stream>>>(w1, wT1, 64, 64);
  wtrans_kernel<<<(9*128*64  + 255)/256, 256, 0, stream>>>(w2, wT2, 128, 64);
  wtrans_kernel<<<(9*256*128 + 255)/256, 256, 0, stream>>>(w3, wT3, 256, 128);
  zero_kernel<<<((BB*256 + 512) + 255)/256, 256, 0, stream>>>(meanb, BB*256 + 512);

  const int nt128 = NP / 128;  // 160 (conv0, conv2, conv3)
  const int nt256 = NP / 256;  // 80  (conv1)

  for (int b0 = 0; b0 < BB; b0 += g) {
    const int gb = (BB - b0 < g) ? (BB - b0) : g;
    const float* Xg = X + (size_t)b0 * TT * VV * CCH;
    const unsigned short* xng = xn + (size_t)b0 * NP * 3;
    float* mg = meanb + (size_t)b0 * 256;

    // adjacency once per group
    adj_kernel<<<gb*TT, 256, 0, stream>>>(Xg, Ab);
    // conv0: xn(3ch) -> P[64][NP]
    conv0_mfma<<<dim3(nt128,1,gb), 256, 0, stream>>>(xng, w0T, cb0, P);
    // layer 1
    gmm_mfma<1><<<gb*TT, 256, 0, stream>>>(Ab, P, Q);
    conv_mfma<64,64,8,1,0><<<nt256*gb, 256, 0, stream>>>(Q, wT1, cb1, P, nullptr, zbuf, 64, nt256, 1);
    // layer 2
    gmm_mfma<1><<<gb*TT, 256, 0, stream>>>(Ab, P, Q);
    conv_mfma<64,128,4,1,0><<<nt128*gb, 256, 0, stream>>>(Q, wT2, cb2, P, nullptr, zbuf, 128, nt128, 1);
    // layer 3: conv3 back to OCB=128 (2 oc-blocks), fused relu+mean
    gmm_mfma<2><<<gb*TT, 256, 0, stream>>>(Ab, P, Q);
    conv_mfma<128,128,4,1,1><<<nt128*2*gb, 256, 0, stream>>>(Q, wT3, cb3, nullptr, mg, zbuf, 256, nt128, 2);
  }

  fc_kernel<<<BB, 256, 0, stream>>>(meanb, fcw, fcb, out);
}